// Round 1
// baseline (376.462 us; speedup 1.0000x reference)
//
#include <hip/hip_runtime.h>

// Fusedmax: out = sparsemax(prox_TV1D(x, alpha=1)) row-wise. B=4096, N=512, fp32.
// Design: one wave (64 threads) per row.
//   1) coalesced float4 load of the row into LDS (2 KB)
//   2) lane 0 runs Condat's direct 1-D TV algorithm serially, IN PLACE in LDS
//      (reads are always ahead of the flush frontier; the only exception is the
//       end-phase clamp nk=min(km+1,N-1) which may re-read index N-1 after it
//       was flushed -> snapshot yLast first, matching the JAX reference which
//       reads pristine y)
//   3) all 64 lanes compute sparsemax via Michelot's support-shrinking fixed
//      point (exact tau, no sort), then coalesced float4 store.

#define TVN 512
#define LAMBDA 1.0f

__device__ __forceinline__ float wave_reduce_sum(float v) {
#pragma unroll
    for (int off = 32; off > 0; off >>= 1) v += __shfl_xor(v, off, 64);
    return v;
}

__global__ __launch_bounds__(64) void fusedmax_kernel(const float* __restrict__ xin,
                                                      float* __restrict__ out) {
    __shared__ float row[TVN];
    const int t = threadIdx.x;                 // 0..63
    const long long r = blockIdx.x;
    const float lam = LAMBDA;

    // ---- stage row into LDS, coalesced (16B/lane) ----
    const float4* __restrict__ g4 = (const float4*)(xin + r * TVN);
    float4* s4 = (float4*)row;
    s4[t] = g4[t];
    s4[t + 64] = g4[t + 64];
    __syncthreads();

    // ---- Condat 1-D TV denoise, serial on lane 0, in place ----
    if (t == 0) {
        const float yLast = row[TVN - 1];
        const float twolam = 2.0f * lam;
        int k = 0, k0 = 0, km = 0, kp = 0;
        float vmin = row[0] - lam, vmax = row[0] + lam;
        float umin = lam, umax = -lam;
        for (;;) {
            if (k == TVN - 1) {
                if (umin < 0.0f) {                       // end-phase negative jump
                    for (int i = k0; i <= km; ++i) row[i] = vmin;
                    int nk = km + 1;
                    float ynk = (nk > TVN - 1) ? yLast : row[nk];
                    if (nk > TVN - 1) nk = TVN - 1;
                    k = k0 = km = nk;
                    vmin = ynk;
                    umin = lam;
                    umax = ynk + lam - vmax;             // old vmax
                } else if (umax > 0.0f) {                // end-phase positive jump
                    for (int i = k0; i <= kp; ++i) row[i] = vmax;
                    int nk = kp + 1;
                    float ynk = (nk > TVN - 1) ? yLast : row[nk];
                    if (nk > TVN - 1) nk = TVN - 1;
                    k = k0 = kp = nk;
                    vmax = ynk;
                    umax = -lam;
                    umin = ynk - lam - vmin;             // old vmin
                } else {                                  // finish
                    float v = vmin + umin / (float)(k - k0 + 1);
                    for (int i = k0; i < TVN; ++i) row[i] = v;
                    break;
                }
            } else {
                float yn = row[k + 1];
                if (yn + umin < vmin - lam) {            // negative jump
                    for (int i = k0; i <= km; ++i) row[i] = vmin;
                    int nk = km + 1;                      // <= N-1, untouched index
                    float ynk = row[nk];
                    k = k0 = km = kp = nk;
                    vmin = ynk;
                    vmax = ynk + twolam;
                    umin = lam;
                    umax = -lam;
                } else if (yn + umax > vmax + lam) {     // positive jump
                    for (int i = k0; i <= kp; ++i) row[i] = vmax;
                    int nk = kp + 1;
                    float ynk = row[nk];
                    k = k0 = km = kp = nk;
                    vmax = ynk;
                    vmin = ynk - twolam;
                    umin = lam;
                    umax = -lam;
                } else {                                  // accumulate
                    ++k;
                    umin += yn - vmin;
                    umax += yn - vmax;
                    if (umin >= lam) {
                        vmin += (umin - lam) / (float)(k - k0 + 1);
                        umin = lam;
                        km = k;
                    }
                    if (umax <= -lam) {
                        vmax += (umax + lam) / (float)(k - k0 + 1);
                        umax = -lam;
                        kp = k;
                    }
                }
            }
        }
    }
    __syncthreads();

    // ---- sparsemax via Michelot fixed point (exact tau, no sort) ----
    float4 a = s4[t];
    float4 b = s4[t + 64];
    float v[8] = {a.x, a.y, a.z, a.w, b.x, b.y, b.z, b.w};

    float ls = v[0] + v[1] + v[2] + v[3] + v[4] + v[5] + v[6] + v[7];
    float S = wave_reduce_sum(ls);
    float tau = (S - 1.0f) * (1.0f / (float)TVN);   // support = all
    int cprev = TVN;
#pragma unroll 1
    for (int it = 0; it < 64; ++it) {
        float s = 0.0f, c = 0.0f;
#pragma unroll
        for (int j = 0; j < 8; ++j) {
            if (v[j] > tau) { s += v[j]; c += 1.0f; }
        }
        s = wave_reduce_sum(s);
        c = wave_reduce_sum(c);               // >= 1 always (tau < max)
        tau = (s - 1.0f) / c;
        int ci = (int)c;
        if (ci == cprev) break;               // support stabilized -> tau exact
        cprev = ci;
    }

    float4 oa, ob;
    oa.x = fmaxf(v[0] - tau, 0.0f);
    oa.y = fmaxf(v[1] - tau, 0.0f);
    oa.z = fmaxf(v[2] - tau, 0.0f);
    oa.w = fmaxf(v[3] - tau, 0.0f);
    ob.x = fmaxf(v[4] - tau, 0.0f);
    ob.y = fmaxf(v[5] - tau, 0.0f);
    ob.z = fmaxf(v[6] - tau, 0.0f);
    ob.w = fmaxf(v[7] - tau, 0.0f);
    float4* __restrict__ o4 = (float4*)(out + r * TVN);
    o4[t] = oa;
    o4[t + 64] = ob;
}

extern "C" void kernel_launch(void* const* d_in, const int* in_sizes, int n_in,
                              void* d_out, int out_size, void* d_ws, size_t ws_size,
                              hipStream_t stream) {
    const float* x = (const float*)d_in[0];
    float* out = (float*)d_out;
    const int rows = in_sizes[0] / TVN;       // 4096
    fusedmax_kernel<<<dim3(rows), dim3(64), 0, stream>>>(x, out);
}